// Round 8
// baseline (1166.330 us; speedup 1.0000x reference)
//
#include <hip/hip_runtime.h>

#define NN 100000
#define EE 1600000
#define RRR 8
#define NSEG (NN*RRR)
#define F 128
#define KDIM 1152          // 8 relations * 128 + self(root) 128
#define NKT 36             // KDIM/32
#define BNEPS 1e-5f

typedef __attribute__((ext_vector_type(8))) short bf16x8;
typedef __attribute__((ext_vector_type(8))) unsigned short u16x8;
typedef __attribute__((ext_vector_type(4))) float f32x4;

static __device__ __forceinline__ unsigned short bf16r(float f) {
  unsigned u = __float_as_uint(f);
  u += 0x7fffu + ((u >> 16) & 1u);
  return (unsigned short)(u >> 16);
}
static __device__ __forceinline__ float b2f(unsigned short s) {
  return __uint_as_float((unsigned)s << 16);
}

// ------------------- preprocessing -------------------
// fused: bf16 convert of x  +  per-(dst,rel) segment count
__global__ __launch_bounds__(256) void k_precnt(const float* __restrict__ x,
    unsigned short* __restrict__ xb, const int* __restrict__ dst,
    const int* __restrict__ et, unsigned* __restrict__ cnt) {
  int idx = blockIdx.x*256 + threadIdx.x;
  if (idx < NN*32) {
    float4 v = ((const float4*)x)[idx];
    ushort4 o;
    o.x = bf16r(v.x); o.y = bf16r(v.y); o.z = bf16r(v.z); o.w = bf16r(v.w);
    ((ushort4*)xb)[idx] = o;
  }
  if (idx < EE)
    atomicAdd(&cnt[dst[idx]*RRR + et[idx]], 1u);
}

__global__ void k_scan1(const unsigned* __restrict__ cnt, unsigned* __restrict__ off,
                        unsigned* __restrict__ bsum) {
  __shared__ unsigned s[256];
  int t = threadIdx.x;
  int base = blockIdx.x*2048 + t*8;
  unsigned loc[8];
  unsigned tot = 0;
#pragma unroll
  for (int j = 0; j < 8; j++) {
    unsigned v = (base+j < NSEG) ? cnt[base+j] : 0u;
    loc[j] = tot;
    tot += v;
  }
  s[t] = tot;
  __syncthreads();
  for (int d = 1; d < 256; d <<= 1) {
    unsigned v = (t >= d) ? s[t-d] : 0u;
    __syncthreads();
    s[t] += v;
    __syncthreads();
  }
  unsigned tbase = s[t] - tot;
#pragma unroll
  for (int j = 0; j < 8; j++)
    if (base+j < NSEG) off[base+j] = tbase + loc[j];
  if (t == 255) bsum[blockIdx.x] = s[255];
}

__global__ void k_scan2(unsigned* bsum, int nb) {
  __shared__ unsigned s[512];
  int t = threadIdx.x;
  unsigned v = (t < nb) ? bsum[t] : 0u;
  s[t] = v;
  __syncthreads();
  for (int d = 1; d < 512; d <<= 1) {
    unsigned u = (t >= d) ? s[t-d] : 0u;
    __syncthreads();
    s[t] += u;
    __syncthreads();
  }
  if (t < nb) bsum[t] = (t == 0) ? 0u : s[t-1];
}

__global__ void k_scan3(unsigned* off, const unsigned* __restrict__ bsum) {
  int i = blockIdx.x*256 + threadIdx.x;
  if (i < NSEG) off[i] += bsum[i >> 11];
}

// fill using off itself as cursor: afterwards off[seg] = segment END;
// consumers recover start = off[seg] - cnt[seg].
__global__ void k_fill(const int* __restrict__ src, const int* __restrict__ dst,
                       const int* __restrict__ et, unsigned* __restrict__ off,
                       int* __restrict__ csr) {
  int e = blockIdx.x*256 + threadIdx.x;
  if (e < EE) {
    int seg = dst[e]*RRR + et[e];
    unsigned pos = atomicAdd(&off[seg], 1u);
    csr[pos] = src[e];
  }
}

// All 3 layers' weights in B-fragment layout, one launch; block(0,0,0)
// also zeroes both BN stats buffers.
__global__ void k_makeW3(const float* __restrict__ b1, const float* __restrict__ c1,
                         const float* __restrict__ r1, const float* __restrict__ b2,
                         const float* __restrict__ c2, const float* __restrict__ r2,
                         const float* __restrict__ b3, const float* __restrict__ c3,
                         const float* __restrict__ r3, unsigned short* __restrict__ WB3,
                         float* __restrict__ stats) {
  int kt = blockIdx.x, ct = blockIdx.y, l = blockIdx.z;
  int lane = threadIdx.x;
  if (kt == 0 && ct == 0 && l == 0) {
#pragma unroll
    for (int j = 0; j < 8; j++) stats[lane*8 + j] = 0.f;
  }
  const float* basis = (l == 0) ? b1 : (l == 1) ? b2 : b3;
  const float* comp  = (l == 0) ? c1 : (l == 1) ? c2 : c3;
  const float* root  = (l == 0) ? r1 : (l == 1) ? r2 : r3;
  int o = ct*16 + (lane & 15);
  int kbase = kt*32 + (lane >> 4)*8;
  unsigned short v[8];
#pragma unroll
  for (int j = 0; j < 8; j++) {
    int k = kbase + j;
    float val;
    if (k < 1024) {
      int r = k >> 7, i = k & 127;
      val = 0.f;
#pragma unroll
      for (int bb = 0; bb < 8; bb++)
        val += comp[r*8+bb] * basis[(bb*F + i)*F + o];
    } else {
      val = root[(k - 1024)*F + o];
    }
    v[j] = bf16r(val);
  }
  unsigned short* dstp = WB3 + (size_t)l*KDIM*F + ((size_t)(kt*8 + ct)*64 + lane)*8;
#pragma unroll
  for (int j = 0; j < 8; j++) dstp[j] = v[j];
}

// ------------------- aggregation -------------------
// Block = 32 segments (4 nodes). Group g (16 lanes) interleaves TWO segments.
// Mean in A-FRAGMENT layout: ushort8 chunk index = (rt*36 + kt)*64 + lane,
//   rt = localrow>>4, lane = (localrow&15) + 16*kg, kt covers channels kt*32+kg*8.
// Relations at kt = r*4 + sl>>2; self row at kt = 32 + sl>>2 (written by r==0 group).
__global__ __launch_bounds__(256) void k_agg(const unsigned short* __restrict__ hb,
    const unsigned* __restrict__ off, const unsigned* __restrict__ cnt,
    const int* __restrict__ csr, unsigned short* __restrict__ Mean, int segBase) {
  int t = threadIdx.x;
  int sl = t & 15, c8 = sl*8;
  int g = t >> 4;
  int s0 = segBase + blockIdx.x*32 + 2*g;
  int s1 = s0 + 1;
  unsigned cA = cnt[s0], cB = cnt[s1];
  unsigned bA = off[s0] - cA, bB = off[s1] - cB;
  const unsigned short* hc = hb + c8;
  float aA[8], aB[8];
#pragma unroll
  for (int u = 0; u < 8; u++) { aA[u] = 0.f; aB[u] = 0.f; }
  unsigned jA = 0, jB = 0;
  while (jA < cA || jB < cB) {
    unsigned nA = cA - jA; if (nA > 2) nA = 2;
    unsigned nB = cB - jB; if (nB > 2) nB = 2;
    int i0 = 0, i1 = 0, i2 = 0, i3 = 0;
    if (nA > 0) i0 = csr[bA + jA];
    if (nA > 1) i1 = csr[bA + jA + 1];
    if (nB > 0) i2 = csr[bB + jB];
    if (nB > 1) i3 = csr[bB + jB + 1];
    if (nA > 0) {
      u16x8 v = *(const u16x8*)&hc[(size_t)i0*F];
#pragma unroll
      for (int u = 0; u < 8; u++) aA[u] += b2f(v[u]);
    }
    if (nA > 1) {
      u16x8 v = *(const u16x8*)&hc[(size_t)i1*F];
#pragma unroll
      for (int u = 0; u < 8; u++) aA[u] += b2f(v[u]);
    }
    if (nB > 0) {
      u16x8 v = *(const u16x8*)&hc[(size_t)i2*F];
#pragma unroll
      for (int u = 0; u < 8; u++) aB[u] += b2f(v[u]);
    }
    if (nB > 1) {
      u16x8 v = *(const u16x8*)&hc[(size_t)i3*F];
#pragma unroll
      for (int u = 0; u < 8; u++) aB[u] += b2f(v[u]);
    }
    jA += nA; jB += nB;
  }
  float ivA = cA ? 1.f/(float)cA : 0.f;
  float ivB = cB ? 1.f/(float)cB : 0.f;
  u16x8 oA, oB;
#pragma unroll
  for (int u = 0; u < 8; u++) { oA[u] = bf16r(aA[u]*ivA); oB[u] = bf16r(aB[u]*ivB); }
  int l0 = s0 - segBase, l1 = s1 - segBase;
  int ktl = sl >> 2, kgl = sl & 3;
  {
    int nl = l0 >> 3, r = l0 & 7;
    size_t ci = ((size_t)((nl >> 4)*NKT + r*4 + ktl)*64 + (nl & 15) + 16*kgl);
    *(u16x8*)&Mean[ci*8] = oA;
    if (r == 0) {  // self row for this node
      size_t cs = ((size_t)((nl >> 4)*NKT + 32 + ktl)*64 + (nl & 15) + 16*kgl);
      *(u16x8*)&Mean[cs*8] = *(const u16x8*)&hb[(size_t)(s0 >> 3)*F + c8];
    }
  }
  {
    int nl = l1 >> 3, r = l1 & 7;
    size_t ci = ((size_t)((nl >> 4)*NKT + r*4 + ktl)*64 + (nl & 15) + 16*kgl);
    *(u16x8*)&Mean[ci*8] = oB;
  }
}

// ------------------- GEMM (+BN stats / +L2 norm) -------------------
// Wave = 16 rows (1 A-frag, rt = blk*4 + wave), A read is a contiguous 36KB
// stream per wave. Block = 64 rows. mode 0: BN stats; mode 1: row L2-norm.
__global__ __launch_bounds__(256) void k_gemm(const unsigned short* __restrict__ Mean,
    const unsigned short* __restrict__ WB, const float* __restrict__ bias,
    float* __restrict__ outp, float* __restrict__ stats,
    int outBase, int count, int mode) {
  __shared__ float s_sum[128];
  __shared__ float s_sq[128];
  int t = threadIdx.x;
  int wave = t >> 6;
  int lane = t & 63;
  int rt = blockIdx.x*4 + wave;
  int rbase = rt*16;              // local row base of this wave
  int rlo = lane & 15;
  int kg = lane >> 4;
  const unsigned short* ap = Mean + ((size_t)rt*NKT*64 + lane)*8;
  const unsigned short* bp = WB + (size_t)lane*8;

  if (mode == 0 && t < 128) { s_sum[t] = 0.f; s_sq[t] = 0.f; }

  f32x4 acc[8];
#pragma unroll
  for (int j = 0; j < 8; j++) acc[j] = (f32x4){0.f,0.f,0.f,0.f};

  for (int kt = 0; kt < NKT; kt++) {
    bf16x8 a = *(const bf16x8*)(ap + (size_t)kt*512);
#pragma unroll
    for (int ct = 0; ct < 8; ct++) {
      bf16x8 b = *(const bf16x8*)(bp + (size_t)(kt*8 + ct)*512);
      acc[ct] = __builtin_amdgcn_mfma_f32_16x16x32_bf16(a, b, acc[ct], 0, 0, 0);
    }
  }

  float bv[8];
#pragma unroll
  for (int ct = 0; ct < 8; ct++) bv[ct] = bias[ct*16 + rlo];

  // C/D layout: col = ct*16 + rlo, row = rbase + kg*4 + i
  if (mode == 0) {
    __syncthreads();
    float psum[8], psq[8];
#pragma unroll
    for (int ct = 0; ct < 8; ct++) { psum[ct] = 0.f; psq[ct] = 0.f; }
#pragma unroll
    for (int i = 0; i < 4; i++) {
      int row = rbase + kg*4 + i;
      if (row < count) {
        float* orow = outp + (size_t)(outBase + row)*F;
#pragma unroll
        for (int ct = 0; ct < 8; ct++) {
          float y = acc[ct][i] + bv[ct];
          orow[ct*16 + rlo] = y;
          psum[ct] += y;
          psq[ct]  += y*y;
        }
      }
    }
#pragma unroll
    for (int ct = 0; ct < 8; ct++) {
      atomicAdd(&s_sum[ct*16 + rlo], psum[ct]);
      atomicAdd(&s_sq [ct*16 + rlo], psq[ct]);
    }
    __syncthreads();
    if (t < 128) {
      atomicAdd(&stats[t],       s_sum[t]);
      atomicAdd(&stats[128 + t], s_sq[t]);
    }
  } else {
#pragma unroll
    for (int i = 0; i < 4; i++) {
      int row = rbase + kg*4 + i;
      float y[8], ss = 0.f;
#pragma unroll
      for (int ct = 0; ct < 8; ct++) {
        y[ct] = acc[ct][i] + bv[ct];
        ss += y[ct]*y[ct];
      }
#pragma unroll
      for (int m = 1; m < 16; m <<= 1)
        ss += __shfl_xor(ss, m, 64);
      float inv = 1.f / fmaxf(sqrtf(ss), 1e-12f);
      if (row < count) {
        float* orow = outp + (size_t)(outBase + row)*F;
#pragma unroll
        for (int ct = 0; ct < 8; ct++)
          orow[ct*16 + rlo] = y[ct]*inv;
      }
    }
  }
}

// BN apply + LeakyReLU -> bf16 table for next layer
__global__ __launch_bounds__(256) void k_bnapply(const float* __restrict__ h,
    const float* __restrict__ stats, const float* __restrict__ gamma,
    const float* __restrict__ beta, unsigned short* __restrict__ outp) {
  int idx = blockIdx.x*256 + threadIdx.x;
  if (idx >= NN*32) return;
  int row = idx >> 5;
  int c4 = (idx & 31) * 4;
  float4 v  = *(const float4*)&h[(size_t)row*F + c4];
  float4 sm = *(const float4*)&stats[c4];
  float4 sq = *(const float4*)&stats[128 + c4];
  float4 gm = *(const float4*)&gamma[c4];
  float4 bt = *(const float4*)&beta[c4];
  const float invN = 1.f / (float)NN;
  ushort4 o;
  { float m = sm.x*invN; float var = sq.x*invN - m*m; float r0 = rsqrtf(var + BNEPS);
    float z = (v.x - m)*r0*gm.x + bt.x; o.x = bf16r((z > 0.f) ? z : 0.1f*z); }
  { float m = sm.y*invN; float var = sq.y*invN - m*m; float r0 = rsqrtf(var + BNEPS);
    float z = (v.y - m)*r0*gm.y + bt.y; o.y = bf16r((z > 0.f) ? z : 0.1f*z); }
  { float m = sm.z*invN; float var = sq.z*invN - m*m; float r0 = rsqrtf(var + BNEPS);
    float z = (v.z - m)*r0*gm.z + bt.z; o.z = bf16r((z > 0.f) ? z : 0.1f*z); }
  { float m = sm.w*invN; float var = sq.w*invN - m*m; float r0 = rsqrtf(var + BNEPS);
    float z = (v.w - m)*r0*gm.w + bt.w; o.w = bf16r((z > 0.f) ? z : 0.1f*z); }
  *(ushort4*)&outp[(size_t)row*F + c4] = o;
}

// ------------------- host launcher -------------------
extern "C" void kernel_launch(void* const* d_in, const int* in_sizes, int n_in,
                              void* d_out, int out_size, void* d_ws, size_t ws_size,
                              hipStream_t stream) {
  const float* x      = (const float*)d_in[0];
  const int*   ei     = (const int*)d_in[1];
  const int*   etp    = (const int*)d_in[2];
  const float* basis[3] = {(const float*)d_in[3], (const float*)d_in[7],  (const float*)d_in[11]};
  const float* comp[3]  = {(const float*)d_in[4], (const float*)d_in[8],  (const float*)d_in[12]};
  const float* root[3]  = {(const float*)d_in[5], (const float*)d_in[9],  (const float*)d_in[13]};
  const float* bias[3]  = {(const float*)d_in[6], (const float*)d_in[10], (const float*)d_in[14]};
  const float* gamma[2] = {(const float*)d_in[15], (const float*)d_in[17]};
  const float* beta[2]  = {(const float*)d_in[16], (const float*)d_in[18]};
  const int* srcv = ei;
  const int* dstv = ei + EE;
  float* out = (float*)d_out;

  char* w = (char*)d_ws;
  size_t p = 0;
  auto take = [&](size_t bytes) -> void* {
    void* q = w + p;
    p = (p + bytes + 255) & ~(size_t)255;
    return q;
  };
  unsigned* cnt   = (unsigned*)take((size_t)NSEG*4);
  unsigned* off   = (unsigned*)take((size_t)NSEG*4);
  int*      csr   = (int*)     take((size_t)EE*4);
  unsigned* bsum  = (unsigned*)take(1024*4);
  unsigned short* WB3 = (unsigned short*)take((size_t)3*KDIM*F*2);
  float*    stats = (float*)   take(512*4);
  float*    wsA   = (float*)   take((size_t)NN*F*4);             // f32 conv out
  unsigned short* wsBb = (unsigned short*)take((size_t)NN*F*2);  // bf16 BN out
  unsigned short* xb   = (unsigned short*)take((size_t)NN*F*2);  // bf16 x
  size_t avail = (ws_size > p) ? (ws_size - p) : 0;
  long long chmax = (long long)(avail / ((size_t)KDIM*2));
  int CH = (chmax > NN) ? NN : (int)(chmax & ~63LL);
  if (CH < 64) CH = 64;
  unsigned short* Mean = (unsigned short*)(w + p);

  // -------- preprocessing --------
  hipMemsetAsync(cnt, 0, (size_t)NSEG*4, stream);
  k_precnt<<<12500, 256, 0, stream>>>(x, xb, dstv, etp, cnt);
  int nb1 = (NSEG + 2047)/2048;
  k_scan1<<<nb1, 256, 0, stream>>>(cnt, off, bsum);
  k_scan2<<<1, 512, 0, stream>>>(bsum, nb1);
  k_scan3<<<(NSEG+255)/256, 256, 0, stream>>>(off, bsum);
  k_fill<<<(EE+255)/256, 256, 0, stream>>>(srcv, dstv, etp, off, csr);
  dim3 gw(NKT, 8, 3);
  k_makeW3<<<gw, 64, 0, stream>>>(basis[0], comp[0], root[0],
                                  basis[1], comp[1], root[1],
                                  basis[2], comp[2], root[2], WB3, stats);

  // -------- 3 layers --------
  for (int l = 0; l < 3; l++) {
    const unsigned short* hin = (l == 0) ? xb : wsBb;
    float* hraw = (l == 2) ? out : wsA;
    int mode = (l == 2) ? 1 : 0;
    const unsigned short* WB = WB3 + (size_t)l*KDIM*F;
    float* st = stats + (size_t)(l == 2 ? 0 : l)*256;
    for (int b0n = 0; b0n < NN; b0n += CH) {
      int cc = NN - b0n; if (cc > CH) cc = CH;
      k_agg<<<cc/4, 256, 0, stream>>>(hin, off, cnt, csr, Mean, b0n*8);
      k_gemm<<<(cc+63)/64, 256, 0, stream>>>(Mean, WB, bias[l], hraw, st, b0n, cc, mode);
    }
    if (l < 2)
      k_bnapply<<<12500, 256, 0, stream>>>(hraw, stats + (size_t)l*256, gamma[l], beta[l], wsBb);
  }
}

// Round 9
// 1096.125 us; speedup vs baseline: 1.0640x; 1.0640x over previous
//
#include <hip/hip_runtime.h>

#define NN 100000
#define EE 1600000
#define RRR 8
#define NSEG (NN*RRR)
#define F 128
#define KDIM 1152          // 8 relations * 128 + self(root) 128
#define NKT 36             // KDIM/32
#define BNEPS 1e-5f

typedef __attribute__((ext_vector_type(8))) short bf16x8;
typedef __attribute__((ext_vector_type(8))) unsigned short u16x8;
typedef __attribute__((ext_vector_type(4))) float f32x4;

static __device__ __forceinline__ unsigned short bf16r(float f) {
  unsigned u = __float_as_uint(f);
  u += 0x7fffu + ((u >> 16) & 1u);
  return (unsigned short)(u >> 16);
}
static __device__ __forceinline__ float b2f(unsigned short s) {
  return __uint_as_float((unsigned)s << 16);
}

// ------------------- preprocessing -------------------
// fused: bf16 convert of x  +  per-(dst,rel) segment count
__global__ __launch_bounds__(256) void k_precnt(const float* __restrict__ x,
    unsigned short* __restrict__ xb, const int* __restrict__ dst,
    const int* __restrict__ et, unsigned* __restrict__ cnt) {
  int idx = blockIdx.x*256 + threadIdx.x;
  if (idx < NN*32) {
    float4 v = ((const float4*)x)[idx];
    ushort4 o;
    o.x = bf16r(v.x); o.y = bf16r(v.y); o.z = bf16r(v.z); o.w = bf16r(v.w);
    ((ushort4*)xb)[idx] = o;
  }
  if (idx < EE)
    atomicAdd(&cnt[dst[idx]*RRR + et[idx]], 1u);
}

__global__ void k_scan1(const unsigned* __restrict__ cnt, unsigned* __restrict__ off,
                        unsigned* __restrict__ bsum) {
  __shared__ unsigned s[256];
  int t = threadIdx.x;
  int base = blockIdx.x*2048 + t*8;
  unsigned loc[8];
  unsigned tot = 0;
#pragma unroll
  for (int j = 0; j < 8; j++) {
    unsigned v = (base+j < NSEG) ? cnt[base+j] : 0u;
    loc[j] = tot;
    tot += v;
  }
  s[t] = tot;
  __syncthreads();
  for (int d = 1; d < 256; d <<= 1) {
    unsigned v = (t >= d) ? s[t-d] : 0u;
    __syncthreads();
    s[t] += v;
    __syncthreads();
  }
  unsigned tbase = s[t] - tot;
#pragma unroll
  for (int j = 0; j < 8; j++)
    if (base+j < NSEG) off[base+j] = tbase + loc[j];
  if (t == 255) bsum[blockIdx.x] = s[255];
}

__global__ void k_scan2(unsigned* bsum, int nb) {
  __shared__ unsigned s[512];
  int t = threadIdx.x;
  unsigned v = (t < nb) ? bsum[t] : 0u;
  s[t] = v;
  __syncthreads();
  for (int d = 1; d < 512; d <<= 1) {
    unsigned u = (t >= d) ? s[t-d] : 0u;
    __syncthreads();
    s[t] += u;
    __syncthreads();
  }
  if (t < nb) bsum[t] = (t == 0) ? 0u : s[t-1];
}

__global__ void k_scan3(unsigned* off, const unsigned* __restrict__ bsum) {
  int i = blockIdx.x*256 + threadIdx.x;
  if (i < NSEG) off[i] += bsum[i >> 11];
}

// fill using off itself as cursor: afterwards off[seg] = segment END;
// consumers recover start = off[seg] - cnt[seg].
__global__ void k_fill(const int* __restrict__ src, const int* __restrict__ dst,
                       const int* __restrict__ et, unsigned* __restrict__ off,
                       int* __restrict__ csr) {
  int e = blockIdx.x*256 + threadIdx.x;
  if (e < EE) {
    int seg = dst[e]*RRR + et[e];
    unsigned pos = atomicAdd(&off[seg], 1u);
    csr[pos] = src[e];
  }
}

// All 3 layers' weights in B-fragment layout, one launch; block(0,0,0)
// also zeroes both BN stats buffers.
__global__ void k_makeW3(const float* __restrict__ b1, const float* __restrict__ c1,
                         const float* __restrict__ r1, const float* __restrict__ b2,
                         const float* __restrict__ c2, const float* __restrict__ r2,
                         const float* __restrict__ b3, const float* __restrict__ c3,
                         const float* __restrict__ r3, unsigned short* __restrict__ WB3,
                         float* __restrict__ stats) {
  int kt = blockIdx.x, ct = blockIdx.y, l = blockIdx.z;
  int lane = threadIdx.x;
  if (kt == 0 && ct == 0 && l == 0) {
#pragma unroll
    for (int j = 0; j < 8; j++) stats[lane*8 + j] = 0.f;
  }
  const float* basis = (l == 0) ? b1 : (l == 1) ? b2 : b3;
  const float* comp  = (l == 0) ? c1 : (l == 1) ? c2 : c3;
  const float* root  = (l == 0) ? r1 : (l == 1) ? r2 : r3;
  int o = ct*16 + (lane & 15);
  int kbase = kt*32 + (lane >> 4)*8;
  unsigned short v[8];
#pragma unroll
  for (int j = 0; j < 8; j++) {
    int k = kbase + j;
    float val;
    if (k < 1024) {
      int r = k >> 7, i = k & 127;
      val = 0.f;
#pragma unroll
      for (int bb = 0; bb < 8; bb++)
        val += comp[r*8+bb] * basis[(bb*F + i)*F + o];
    } else {
      val = root[(k - 1024)*F + o];
    }
    v[j] = bf16r(val);
  }
  unsigned short* dstp = WB3 + (size_t)l*KDIM*F + ((size_t)(kt*8 + ct)*64 + lane)*8;
#pragma unroll
  for (int j = 0; j < 8; j++) dstp[j] = v[j];
}

// ------------------- aggregation (+inline BN/LeakyReLU of INPUT) -------------------
// Block = 4 nodes x 8 rels = 32 segments. Group g (16 lanes): node = blk*4+(g&3),
// rel pair = {2*(g>>2), 2*(g>>2)+1}, interleaved 2-at-a-time gathers.
// KEY: the 4 groups of one WAVE cover 4 CONSECUTIVE nodes at the same rel, so
// their 16B fragment writes form full 64B lines written by one wave.
// Mean in A-fragment layout: chunk idx (rt*NKT + kt)*64 + (nl&15) + 16*kgl,
//   kt = r*4 + (sl>>2) for relations, 32 + (sl>>2) for self row (rp==0 writes).
// BN of input applied inline: z = v*sc+sh, y = max(z, lk*z); lk=1,sc=1,sh=0 when !hasBN.
__global__ __launch_bounds__(256) void k_agg(const unsigned short* __restrict__ hb,
    const unsigned* __restrict__ off, const unsigned* __restrict__ cnt,
    const int* __restrict__ csr, unsigned short* __restrict__ Mean,
    const float* __restrict__ stats, const float* __restrict__ gamma,
    const float* __restrict__ beta, int nodeBase, int hasBN) {
  int t = threadIdx.x;
  int sl = t & 15, c8 = sl*8;
  int g = t >> 4;
  int nl = blockIdx.x*4 + (g & 3);
  int node = nodeBase + nl;
  int rp = g >> 2;
  float sc[8], sh[8];
  float lk = hasBN ? 0.1f : 1.0f;
  if (hasBN) {
    const float invN = 1.f/(float)NN;
#pragma unroll
    for (int u = 0; u < 8; u++) {
      float m = stats[c8+u]*invN;
      float var = stats[128+c8+u]*invN - m*m;
      float rs = rsqrtf(var + BNEPS);
      float gg = gamma[c8+u]*rs;
      sc[u] = gg;
      sh[u] = beta[c8+u] - m*gg;
    }
  } else {
#pragma unroll
    for (int u = 0; u < 8; u++) { sc[u] = 1.f; sh[u] = 0.f; }
  }
  int s0 = node*RRR + 2*rp;
  unsigned cA = cnt[s0], cB = cnt[s0+1];
  unsigned bA = off[s0] - cA, bB = off[s0+1] - cB;
  const unsigned short* hc = hb + c8;
  float aA[8], aB[8];
#pragma unroll
  for (int u = 0; u < 8; u++) { aA[u] = 0.f; aB[u] = 0.f; }
  unsigned jA = 0, jB = 0;
  while (jA < cA || jB < cB) {
    unsigned nA = cA - jA; if (nA > 2) nA = 2;
    unsigned nB = cB - jB; if (nB > 2) nB = 2;
    int i0 = 0, i1 = 0, i2 = 0, i3 = 0;
    if (nA > 0) i0 = csr[bA + jA];
    if (nA > 1) i1 = csr[bA + jA + 1];
    if (nB > 0) i2 = csr[bB + jB];
    if (nB > 1) i3 = csr[bB + jB + 1];
    if (nA > 0) {
      u16x8 v = *(const u16x8*)&hc[(size_t)i0*F];
#pragma unroll
      for (int u = 0; u < 8; u++) { float z = b2f(v[u])*sc[u]+sh[u]; aA[u] += fmaxf(z, lk*z); }
    }
    if (nA > 1) {
      u16x8 v = *(const u16x8*)&hc[(size_t)i1*F];
#pragma unroll
      for (int u = 0; u < 8; u++) { float z = b2f(v[u])*sc[u]+sh[u]; aA[u] += fmaxf(z, lk*z); }
    }
    if (nB > 0) {
      u16x8 v = *(const u16x8*)&hc[(size_t)i2*F];
#pragma unroll
      for (int u = 0; u < 8; u++) { float z = b2f(v[u])*sc[u]+sh[u]; aB[u] += fmaxf(z, lk*z); }
    }
    if (nB > 1) {
      u16x8 v = *(const u16x8*)&hc[(size_t)i3*F];
#pragma unroll
      for (int u = 0; u < 8; u++) { float z = b2f(v[u])*sc[u]+sh[u]; aB[u] += fmaxf(z, lk*z); }
    }
    jA += nA; jB += nB;
  }
  float ivA = cA ? 1.f/(float)cA : 0.f;
  float ivB = cB ? 1.f/(float)cB : 0.f;
  u16x8 oA, oB;
#pragma unroll
  for (int u = 0; u < 8; u++) { oA[u] = bf16r(aA[u]*ivA); oB[u] = bf16r(aB[u]*ivB); }
  int ktl = sl >> 2, kgl = sl & 3;
  int rt = nl >> 4;
  int lraw = (nl & 15) + 16*kgl;
  size_t ciA = ((size_t)(rt*NKT + (2*rp  )*4 + ktl)*64 + lraw)*8;
  size_t ciB = ((size_t)(rt*NKT + (2*rp+1)*4 + ktl)*64 + lraw)*8;
  *(u16x8*)&Mean[ciA] = oA;
  *(u16x8*)&Mean[ciB] = oB;
  if (rp == 0) {   // self row (BN'd input of this node)
    u16x8 v = *(const u16x8*)&hc[(size_t)node*F];
    u16x8 os;
#pragma unroll
    for (int u = 0; u < 8; u++) {
      float z = b2f(v[u])*sc[u] + sh[u];
      os[u] = bf16r(fmaxf(z, lk*z));
    }
    size_t cs = ((size_t)(rt*NKT + 32 + ktl)*64 + lraw)*8;
    *(u16x8*)&Mean[cs] = os;
  }
}

// ------------------- GEMM (+BN stats -> bf16 h  /  +L2 norm -> f32 out) ---------
// Wave = 16 rows (1 A-frag, rt = blk*4 + wave), contiguous A stream.
// mode 0: write bf16 h + accumulate BN stats. mode 1: fused row L2-norm -> f32.
__global__ __launch_bounds__(256) void k_gemm(const unsigned short* __restrict__ Mean,
    const unsigned short* __restrict__ WB, const float* __restrict__ bias,
    unsigned short* __restrict__ houtb, float* __restrict__ foutp,
    float* __restrict__ stats, int outBase, int count, int mode) {
  __shared__ float s_sum[128];
  __shared__ float s_sq[128];
  int t = threadIdx.x;
  int wave = t >> 6;
  int lane = t & 63;
  int rt = blockIdx.x*4 + wave;
  int rbase = rt*16;
  int rlo = lane & 15;
  int kg = lane >> 4;
  const unsigned short* ap = Mean + ((size_t)rt*NKT*64 + lane)*8;
  const unsigned short* bp = WB + (size_t)lane*8;

  if (mode == 0 && t < 128) { s_sum[t] = 0.f; s_sq[t] = 0.f; }

  f32x4 acc[8];
#pragma unroll
  for (int j = 0; j < 8; j++) acc[j] = (f32x4){0.f,0.f,0.f,0.f};

  for (int kt = 0; kt < NKT; kt++) {
    bf16x8 a = *(const bf16x8*)(ap + (size_t)kt*512);
#pragma unroll
    for (int ct = 0; ct < 8; ct++) {
      bf16x8 b = *(const bf16x8*)(bp + (size_t)(kt*8 + ct)*512);
      acc[ct] = __builtin_amdgcn_mfma_f32_16x16x32_bf16(a, b, acc[ct], 0, 0, 0);
    }
  }

  float bv[8];
#pragma unroll
  for (int ct = 0; ct < 8; ct++) bv[ct] = bias[ct*16 + rlo];

  // C/D layout: col = ct*16 + rlo, row = rbase + kg*4 + i
  if (mode == 0) {
    __syncthreads();
    float psum[8], psq[8];
#pragma unroll
    for (int ct = 0; ct < 8; ct++) { psum[ct] = 0.f; psq[ct] = 0.f; }
#pragma unroll
    for (int i = 0; i < 4; i++) {
      int row = rbase + kg*4 + i;
      if (row < count) {
        unsigned short* orow = houtb + (size_t)(outBase + row)*F;
#pragma unroll
        for (int ct = 0; ct < 8; ct++) {
          float y = acc[ct][i] + bv[ct];
          orow[ct*16 + rlo] = bf16r(y);
          psum[ct] += y;
          psq[ct]  += y*y;
        }
      }
    }
#pragma unroll
    for (int ct = 0; ct < 8; ct++) {
      atomicAdd(&s_sum[ct*16 + rlo], psum[ct]);
      atomicAdd(&s_sq [ct*16 + rlo], psq[ct]);
    }
    __syncthreads();
    if (t < 128) {
      atomicAdd(&stats[t],       s_sum[t]);
      atomicAdd(&stats[128 + t], s_sq[t]);
    }
  } else {
#pragma unroll
    for (int i = 0; i < 4; i++) {
      int row = rbase + kg*4 + i;
      float y[8], ss = 0.f;
#pragma unroll
      for (int ct = 0; ct < 8; ct++) {
        y[ct] = acc[ct][i] + bv[ct];
        ss += y[ct]*y[ct];
      }
#pragma unroll
      for (int m = 1; m < 16; m <<= 1)
        ss += __shfl_xor(ss, m, 64);
      float inv = 1.f / fmaxf(sqrtf(ss), 1e-12f);
      if (row < count) {
        float* orow = foutp + (size_t)(outBase + row)*F;
#pragma unroll
        for (int ct = 0; ct < 8; ct++)
          orow[ct*16 + rlo] = y[ct]*inv;
      }
    }
  }
}

// ------------------- host launcher -------------------
extern "C" void kernel_launch(void* const* d_in, const int* in_sizes, int n_in,
                              void* d_out, int out_size, void* d_ws, size_t ws_size,
                              hipStream_t stream) {
  const float* x      = (const float*)d_in[0];
  const int*   ei     = (const int*)d_in[1];
  const int*   etp    = (const int*)d_in[2];
  const float* basis[3] = {(const float*)d_in[3], (const float*)d_in[7],  (const float*)d_in[11]};
  const float* comp[3]  = {(const float*)d_in[4], (const float*)d_in[8],  (const float*)d_in[12]};
  const float* root[3]  = {(const float*)d_in[5], (const float*)d_in[9],  (const float*)d_in[13]};
  const float* bias[3]  = {(const float*)d_in[6], (const float*)d_in[10], (const float*)d_in[14]};
  const float* gamma[2] = {(const float*)d_in[15], (const float*)d_in[17]};
  const float* beta[2]  = {(const float*)d_in[16], (const float*)d_in[18]};
  const int* srcv = ei;
  const int* dstv = ei + EE;
  float* out = (float*)d_out;

  char* w = (char*)d_ws;
  size_t p = 0;
  auto take = [&](size_t bytes) -> void* {
    void* q = w + p;
    p = (p + bytes + 255) & ~(size_t)255;
    return q;
  };
  unsigned* cnt   = (unsigned*)take((size_t)NSEG*4);
  unsigned* off   = (unsigned*)take((size_t)NSEG*4);
  int*      csr   = (int*)     take((size_t)EE*4);
  unsigned* bsum  = (unsigned*)take(1024*4);
  unsigned short* WB3 = (unsigned short*)take((size_t)3*KDIM*F*2);
  float*    stats = (float*)   take(512*4);
  unsigned short* hbuf0 = (unsigned short*)take((size_t)NN*F*2);  // bf16 h after layer 1
  unsigned short* hbuf1 = (unsigned short*)take((size_t)NN*F*2);  // bf16 h after layer 2
  unsigned short* xb    = (unsigned short*)take((size_t)NN*F*2);  // bf16 x
  size_t avail = (ws_size > p) ? (ws_size - p) : 0;
  long long rows = (long long)(avail / ((size_t)KDIM*2)) - 64;    // pad 64 rows for tail reads
  int CH = (rows > NN) ? NN : (int)(rows & ~63LL);
  if (CH < 64) CH = 64;
  unsigned short* Mean = (unsigned short*)(w + p);

  // -------- preprocessing --------
  hipMemsetAsync(cnt, 0, (size_t)NSEG*4, stream);
  k_precnt<<<12500, 256, 0, stream>>>(x, xb, dstv, etp, cnt);
  int nb1 = (NSEG + 2047)/2048;
  k_scan1<<<nb1, 256, 0, stream>>>(cnt, off, bsum);
  k_scan2<<<1, 512, 0, stream>>>(bsum, nb1);
  k_scan3<<<(NSEG+255)/256, 256, 0, stream>>>(off, bsum);
  k_fill<<<(EE+255)/256, 256, 0, stream>>>(srcv, dstv, etp, off, csr);
  dim3 gw(NKT, 8, 3);
  k_makeW3<<<gw, 64, 0, stream>>>(basis[0], comp[0], root[0],
                                  basis[1], comp[1], root[1],
                                  basis[2], comp[2], root[2], WB3, stats);

  // -------- 3 layers --------
  for (int l = 0; l < 3; l++) {
    const unsigned short* hin = (l == 0) ? xb : ((l == 1) ? hbuf0 : hbuf1);
    unsigned short* hout = (l == 0) ? hbuf0 : hbuf1;   // unused for l==2
    const unsigned short* WB = WB3 + (size_t)l*KDIM*F;
    int mode = (l == 2) ? 1 : 0;
    float* st_out = stats + (size_t)(l < 2 ? l : 0)*256;
    const float* st_in = (l > 0) ? (stats + (size_t)(l-1)*256) : stats;
    const float* gm = (l > 0) ? gamma[l-1] : gamma[0];
    const float* bt = (l > 0) ? beta[l-1]  : beta[0];
    for (int b0n = 0; b0n < NN; b0n += CH) {
      int cc = NN - b0n; if (cc > CH) cc = CH;
      k_agg<<<cc/4, 256, 0, stream>>>(hin, off, cnt, csr, Mean, st_in, gm, bt, b0n, l > 0);
      k_gemm<<<(cc+63)/64, 256, 0, stream>>>(Mean, WB, bias[l], hout, out, st_out, b0n, cc, mode);
    }
  }
}